// Round 13
// baseline (51.009 us; speedup 1.0000x reference)
//
#include <hip/hip_runtime.h>
#include <hip/hip_bf16.h>

#define RES 7
#define NCH 256

__device__ __forceinline__ unsigned short f32_to_bf16_rne(float f) {
    unsigned int u = __float_as_uint(f);
    u += 0x7fffu + ((u >> 16) & 1u);
    return (unsigned short)(u >> 16);
}

__device__ __forceinline__ unsigned int pack_bf16x2(float lo, float hi) {
    return (unsigned int)f32_to_bf16_rne(lo) | ((unsigned int)f32_to_bf16_rne(hi) << 16);
}

// ---------------------------------------------------------------------------
// Pass 1 v10: NCHW fp32 -> NHWC bf16 via global_load_lds DMA.
// Tile = 128 hw x 64 c per block, 512 thr. Each wave issues 4 back-to-back
// 1KB global_load_lds (intrinsic cannot be sunk by the compiler -> 4KB/wave
// guaranteed in flight; r9/r11/r12 showed register-load paths were always
// serialized ~2-deep by IR-level sinking or miscompiled via asm).
// LDS layout: 32 row-pair groups, stride 1040B (16B-aligned; <=4-way bank
// conflict on the transposed phase-2 read). Tails + f3 (HW=625, not 16B-
// alignable) use the known-correct scalar path.
// ---------------------------------------------------------------------------
__global__ __launch_bounds__(512) void transpose_dma_bf16(
    const float* __restrict__ f0, const float* __restrict__ f1,
    const float* __restrict__ f2, const float* __restrict__ f3,
    unsigned short* __restrict__ ws)
{
    __shared__ float ldsf[32 * 260];           // 33,280 B

    const int xt = blockIdx.x;                 // 0..416  hw128-tile prefix
    const int cy = blockIdx.y;                 // 0..3   -> channels 64*cy..
    const int b  = blockIdx.z;

    // per-level hw128-tile prefix: f0:313, f1:79, f2:20, f3:5 (total 417)
    const int l    = (xt >= 313) + (xt >= 392) + (xt >= 412);
    const int base = (l == 0) ? 0 : (l == 1) ? 313 : (l == 2) ? 392 : 412;
    const int HW   = (l == 0) ? 40000 : (l == 1) ? 10000 : (l == 2) ? 2500 : 625;
    const float* __restrict__ src =
        (l == 0) ? f0 : (l == 1) ? f1 : (l == 2) ? f2 : f3;
    const size_t doff = (l == 0) ? 0u : (l == 1) ? 20480000u
                      : (l == 2) ? 25600000u : 26880000u;

    const int hw0 = (xt - base) * 128;
    const int c0b = 64 * cy;

    const float* __restrict__ s    = src + (size_t)b * NCH * HW;
    unsigned short* __restrict__ d = ws + doff + (size_t)b * HW * NCH;

    const int t  = threadIdx.x;
    const int w  = t >> 6;        // wave 0..7
    const int ln = t & 63;        // lane

    const bool dma = (hw0 + 128 <= HW) && ((HW & 3) == 0);

    if (dma) {
        // wave w stages row-pair groups g = 4w..4w+3; lanes 0-31 -> row 2g,
        // lanes 32-63 -> row 2g+1; each lane loads 16B of its row's hw span.
#pragma unroll
        for (int q = 0; q < 4; ++q) {
            const int g = w * 4 + q;
            const int c = c0b + 2 * g + (ln >> 5);
            const float* gp = s + (size_t)c * HW + hw0 + (ln & 31) * 4;
            float* lp = &ldsf[g * 260];        // wave-uniform base, 16B aligned
            __builtin_amdgcn_global_load_lds(
                (const __attribute__((address_space(1))) void*)gp,
                (__attribute__((address_space(3))) void*)lp,
                16, 0, 0);
        }
    } else {
        // scalar fallback: thread = (hw-quad, channel-quad)
        const int hq  = t & 31;   // 32 quads = 128 hw
        const int cr  = t >> 5;   // 0..15 -> channels 4cr..4cr+3 (local)
        const int hwq = hw0 + 4 * hq;
        float va[4][4];
#pragma unroll
        for (int i = 0; i < 4; ++i)
#pragma unroll
            for (int j = 0; j < 4; ++j)
                va[i][j] = (hwq + j < HW)
                         ? s[(size_t)(c0b + 4 * cr + i) * HW + hwq + j] : 0.0f;
#pragma unroll
        for (int i = 0; i < 4; ++i) {
            const int c = 4 * cr + i;         // local channel 0..63
#pragma unroll
            for (int j = 0; j < 4; ++j)
                ldsf[(c >> 1) * 260 + (c & 1) * 128 + 4 * hq + j] = va[i][j];
        }
    }
    __syncthreads();   // compiler tracks global_load_lds -> emits vmcnt drain

    // phase 2: 2048 uint2; per wave-instr = 4 hw rows x full 128B segment
#pragma unroll
    for (int it = 0; it < 4; ++it) {
        const int idx = t + 512 * it;    // 0..2047
        const int row = idx >> 4;        // local hw 0..127
        const int u   = idx & 15;        // channel-quad 0..15
        const int hw  = hw0 + row;
        if (hw < HW) {
            const float v0 = ldsf[(2 * u) * 260 + row];          // c = 4u
            const float v1 = ldsf[(2 * u) * 260 + 128 + row];    // c = 4u+1
            const float v2 = ldsf[(2 * u + 1) * 260 + row];      // c = 4u+2
            const float v3 = ldsf[(2 * u + 1) * 260 + 128 + row];// c = 4u+3
            uint2 p;
            p.x = pack_bf16x2(v0, v1);
            p.y = pack_bf16x2(v2, v3);
            *(uint2*)(d + (size_t)hw * NCH + c0b + 4 * u) = p;
        }
    }
}

// ---------------------------------------------------------------------------
// Pass 2: one block per ROI, 512 threads (8 waves).
// Lane = channel-quad (uint2 = 4 bf16); bins strided over 8 groups.
// ---------------------------------------------------------------------------
__global__ __launch_bounds__(512) void roi_gather_nhwc_bf16(
    const unsigned short* __restrict__ ws,
    const float* __restrict__ boxes, const int* __restrict__ bidx,
    float* __restrict__ out)
{
    __shared__ float lds[49 * 260];

    const int r   = blockIdx.x;
    const int t   = threadIdx.x;
    const int cq  = t & 63;
    const int grp = t >> 6;

    const float bx1 = boxes[r * 4 + 0];
    const float by1 = boxes[r * 4 + 1];
    const float bx2 = boxes[r * 4 + 2];
    const float by2 = boxes[r * 4 + 3];

    const float area = fmaxf(bx2 - bx1, 0.0f) * fmaxf(by2 - by1, 0.0f);
    const float s    = sqrtf(area);
    const float lvlf = floorf(4.0f + log2f(s / 224.0f + 1e-6f));
    const int   lvl  = (int)(fminf(fmaxf(lvlf, 2.0f), 5.0f)) - 2;

    float scale; int H; size_t off;
    if      (lvl == 0) { scale = 0.25f;    H = 200; off = 0u; }
    else if (lvl == 1) { scale = 0.125f;   H = 100; off = 20480000u; }
    else if (lvl == 2) { scale = 0.0625f;  H = 50;  off = 25600000u; }
    else               { scale = 0.03125f; H = 25;  off = 26880000u; }
    const int W = H;

    const int b = bidx[r];
    const unsigned short* __restrict__ feat = ws + off + (size_t)b * H * W * NCH;

    const float x1 = bx1 * scale;
    const float y1 = by1 * scale;
    const float roi_w = fmaxf(bx2 * scale - x1, 1.0f);
    const float roi_h = fmaxf(by2 * scale - y1, 1.0f);
    const float bw = roi_w * (1.0f / RES);
    const float bh = roi_h * (1.0f / RES);

    for (int bin = grp; bin < 49; bin += 8) {
        const int py = bin / 7;
        const int px = bin - py * 7;

        float acc0 = 0.0f, acc1 = 0.0f, acc2 = 0.0f, acc3 = 0.0f;
#pragma unroll
        for (int sy = 0; sy < 2; ++sy) {
            const float pyf = (float)py + ((float)sy + 0.5f) * 0.5f;
            const float ysmp = y1 + pyf * bh;
            const bool  vy   = (ysmp >= -1.0f) && (ysmp <= (float)H);
            const float ycl  = fminf(fmaxf(ysmp, 0.0f), (float)(H - 1));
            const int   y0   = (int)floorf(ycl);
            const int   y1i  = min(y0 + 1, H - 1);
            const float ly   = ycl - (float)y0;
            const float hy   = 1.0f - ly;
#pragma unroll
            for (int sx = 0; sx < 2; ++sx) {
                const float pxf = (float)px + ((float)sx + 0.5f) * 0.5f;
                const float xsmp = x1 + pxf * bw;
                const bool  vx   = (xsmp >= -1.0f) && (xsmp <= (float)W);
                const float xcl  = fminf(fmaxf(xsmp, 0.0f), (float)(W - 1));
                const int   x0   = (int)floorf(xcl);
                const int   x1i  = min(x0 + 1, W - 1);
                const float lx   = xcl - (float)x0;
                const float hx   = 1.0f - lx;

                const float m   = (vy && vx) ? 1.0f : 0.0f;
                const float w00 = m * hy * hx;
                const float w01 = m * hy * lx;
                const float w10 = m * ly * hx;
                const float w11 = m * ly * lx;

                const uint2 u00 = *(const uint2*)(feat + ((size_t)(y0  * W + x0 )) * NCH + 4 * cq);
                const uint2 u01 = *(const uint2*)(feat + ((size_t)(y0  * W + x1i)) * NCH + 4 * cq);
                const uint2 u10 = *(const uint2*)(feat + ((size_t)(y1i * W + x0 )) * NCH + 4 * cq);
                const uint2 u11 = *(const uint2*)(feat + ((size_t)(y1i * W + x1i)) * NCH + 4 * cq);

                acc0 += w00 * __uint_as_float(u00.x << 16)
                      + w01 * __uint_as_float(u01.x << 16)
                      + w10 * __uint_as_float(u10.x << 16)
                      + w11 * __uint_as_float(u11.x << 16);
                acc1 += w00 * __uint_as_float(u00.x & 0xffff0000u)
                      + w01 * __uint_as_float(u01.x & 0xffff0000u)
                      + w10 * __uint_as_float(u10.x & 0xffff0000u)
                      + w11 * __uint_as_float(u11.x & 0xffff0000u);
                acc2 += w00 * __uint_as_float(u00.y << 16)
                      + w01 * __uint_as_float(u01.y << 16)
                      + w10 * __uint_as_float(u10.y << 16)
                      + w11 * __uint_as_float(u11.y << 16);
                acc3 += w00 * __uint_as_float(u00.y & 0xffff0000u)
                      + w01 * __uint_as_float(u01.y & 0xffff0000u)
                      + w10 * __uint_as_float(u10.y & 0xffff0000u)
                      + w11 * __uint_as_float(u11.y & 0xffff0000u);
            }
        }
        float4* dst = (float4*)&lds[bin * 260 + 4 * cq];
        *dst = make_float4(acc0 * 0.25f, acc1 * 0.25f, acc2 * 0.25f, acc3 * 0.25f);
    }

    __syncthreads();

    float* __restrict__ o = out + (size_t)r * (NCH * 49);
    for (int i = t; i < NCH * 49; i += 512) {
        const int ch = i / 49;
        const int bn = i - ch * 49;
        o[i] = lds[bn * 260 + ch];
    }
}

// ---------------------------------------------------------------------------
// Fallback (round-1 kernel) if d_ws is too small for the NHWC bf16 copy.
// ---------------------------------------------------------------------------
__global__ __launch_bounds__(256) void roi_align_fpn_kernel(
    const float* __restrict__ f0, const float* __restrict__ f1,
    const float* __restrict__ f2, const float* __restrict__ f3,
    const float* __restrict__ boxes, const int* __restrict__ bidx,
    float* __restrict__ out)
{
    const int r   = blockIdx.x;
    const int bin = blockIdx.y;
    const int c   = threadIdx.x;
    const int py  = bin / RES;
    const int px  = bin - py * RES;

    const float bx1 = boxes[r * 4 + 0];
    const float by1 = boxes[r * 4 + 1];
    const float bx2 = boxes[r * 4 + 2];
    const float by2 = boxes[r * 4 + 3];

    const float area = fmaxf(bx2 - bx1, 0.0f) * fmaxf(by2 - by1, 0.0f);
    const float s    = sqrtf(area);
    const float lvlf = floorf(4.0f + log2f(s / 224.0f + 1e-6f));
    const int   lvl  = (int)(fminf(fmaxf(lvlf, 2.0f), 5.0f)) - 2;

    const float scales[4] = {0.25f, 0.125f, 0.0625f, 0.03125f};
    const int   Hs[4]     = {200, 100, 50, 25};
    const float* feats[4] = {f0, f1, f2, f3};

    const float scale = scales[lvl];
    const int   H     = Hs[lvl];
    const int   W     = H;
    const float* feat = feats[lvl];

    const int b = bidx[r];

    const float x1 = bx1 * scale;
    const float y1 = by1 * scale;
    const float roi_w = fmaxf(bx2 * scale - x1, 1.0f);
    const float roi_h = fmaxf(by2 * scale - y1, 1.0f);
    const float bw = roi_w * (1.0f / RES);
    const float bh = roi_h * (1.0f / RES);

    const float* __restrict__ fc = feat + (size_t)(b * NCH + c) * H * W;

    float acc = 0.0f;
#pragma unroll
    for (int sy = 0; sy < 2; ++sy) {
        const float pyf = (float)py + ((float)sy + 0.5f) * 0.5f;
        const float ys  = y1 + pyf * bh;
        const bool  vy  = (ys >= -1.0f) && (ys <= (float)H);
        const float ycl = fminf(fmaxf(ys, 0.0f), (float)(H - 1));
        const int   y0  = (int)floorf(ycl);
        const int   y1i = min(y0 + 1, H - 1);
        const float ly  = ycl - (float)y0;
        const float hy  = 1.0f - ly;
#pragma unroll
        for (int sx = 0; sx < 2; ++sx) {
            const float pxf = (float)px + ((float)sx + 0.5f) * 0.5f;
            const float xs  = x1 + pxf * bw;
            const bool  vx  = (xs >= -1.0f) && (xs <= (float)W);
            const float xcl = fminf(fmaxf(xs, 0.0f), (float)(W - 1));
            const int   x0  = (int)floorf(xcl);
            const int   x1i = min(x0 + 1, W - 1);
            const float lx  = xcl - (float)x0;
            const float hx  = 1.0f - lx;

            const float v00 = fc[y0  * W + x0 ];
            const float v01 = fc[y0  * W + x1i];
            const float v10 = fc[y1i * W + x0 ];
            const float v11 = fc[y1i * W + x1i];

            const float v = v00 * (hy * hx) + v01 * (hy * lx)
                          + v10 * (ly * hx) + v11 * (ly * lx);
            if (vy && vx) acc += v;
        }
    }

    out[((size_t)r * NCH + c) * (RES * RES) + bin] = acc * 0.25f;
}

extern "C" void kernel_launch(void* const* d_in, const int* in_sizes, int n_in,
                              void* d_out, int out_size, void* d_ws, size_t ws_size,
                              hipStream_t stream)
{
    const float* f0    = (const float*)d_in[0];
    const float* f1    = (const float*)d_in[1];
    const float* f2    = (const float*)d_in[2];
    const float* f3    = (const float*)d_in[3];
    const float* boxes = (const float*)d_in[4];
    const int*   bidx  = (const int*)d_in[5];
    float* out = (float*)d_out;

    const int R = in_sizes[4] / 4;  // 512 boxes

    const size_t need = 27200000ull * sizeof(unsigned short);  // bf16 NHWC copy

    if (ws_size >= need) {
        unsigned short* ws = (unsigned short*)d_ws;
        transpose_dma_bf16<<<dim3(417, 4, 2), dim3(512), 0, stream>>>(f0, f1, f2, f3, ws);
        roi_gather_nhwc_bf16<<<dim3(R), dim3(512), 0, stream>>>(ws, boxes, bidx, out);
    } else {
        dim3 grid(R, RES * RES);
        roi_align_fpn_kernel<<<grid, dim3(NCH), 0, stream>>>(f0, f1, f2, f3, boxes, bidx, out);
    }
}